// Round 10
// baseline (1805.218 us; speedup 1.0000x reference)
//
#include <hip/hip_runtime.h>
#include <hip/hip_bf16.h>

typedef __attribute__((ext_vector_type(8))) unsigned short us8;
typedef __attribute__((ext_vector_type(8))) __bf16 bf16x8;
typedef __attribute__((ext_vector_type(4))) float f32x4;

__device__ __forceinline__ unsigned short f2bf(float f) {
  unsigned int u = __float_as_uint(f);
  u += 0x7FFFu + ((u >> 16) & 1u);   // round-to-nearest-even
  return (unsigned short)(u >> 16);
}
__device__ __forceinline__ float bf2f(unsigned short u) {
  return __uint_as_float(((unsigned int)u) << 16);
}

// direct global->LDS DMA, 16B per lane (dest = wave-uniform base + lane*16)
__device__ __forceinline__ void gld16(const unsigned short* g, unsigned short* l) {
  __builtin_amdgcn_global_load_lds(reinterpret_cast<const unsigned int*>(g),
                                   reinterpret_cast<unsigned int*>(l), 16, 0, 0);
}

// ---------------------------------------------------------------------------
// ws layout (bytes)
//   Apad : [2][132][132][256] bf16 = 17,842,176
//   BT   : [256][6400] bf16 (k=(dh*5+dw)*256+c)
//   Pp   : 2 or 4 x [32768][256] bf16 partials (16,777,216 B each)
// splitK2 total = 54,673,408 ; splitK4 total = 88,227,840
// ---------------------------------------------------------------------------
#define BT_OFF     17842176
#define PP_OFF     21118976
#define SK4_BYTES  88227840ull

// --- K1: fused conv1 (blocks 0..4095) + weight prep (4096..4351) +
//         halo zero (4352..4611) --------------------------------------------
__global__ __launch_bounds__(256) void pre_k(const float* __restrict__ x,
                                             const float* __restrict__ W1,
                                             const float* __restrict__ b1,
                                             const float* __restrict__ Wp,
                                             unsigned short* __restrict__ BT,
                                             unsigned short* __restrict__ Apad) {
  __shared__ float w[6400];
  const int bid = blockIdx.x, t = threadIdx.x;
  if (bid < 4096) {
    int pxt = bid >> 3;
    int cq  = bid & 7;
    int px  = (pxt << 6) + (t & 63);
    int cg  = __builtin_amdgcn_readfirstlane(t >> 6);
    int co0 = (cq << 5) + (cg << 3);
    int b = px >> 14, hw = px & 16383;
    int h = hw >> 7, wcol = hw & 127;

    float patch[25];
#pragma unroll
    for (int dh = 0; dh < 5; ++dh)
#pragma unroll
      for (int dw = 0; dw < 5; ++dw) {
        int hh = h + dh - 2, ww = wcol + dw - 2;
        bool ok = (hh >= 0) & (hh < 128) & (ww >= 0) & (ww < 128);
        patch[dh * 5 + dw] = ok ? x[(b << 14) + hh * 128 + ww] : 0.f;
      }
    us8 o;
#pragma unroll
    for (int c = 0; c < 8; ++c) {
      float acc = b1[co0 + c];
#pragma unroll
      for (int i = 0; i < 25; ++i) acc += patch[i] * W1[(co0 + c) * 25 + i];
      o[c] = f2bf(fmaxf(acc, 0.f));
    }
    *(us8*)(Apad + (size_t)((b * 132 + h + 2) * 132 + (wcol + 2)) * 256 + co0) = o;
  } else if (bid < 4352) {
    const int n = bid - 4096;
    const float* src = Wp + n * 6400;
    for (int i = t; i < 6400; i += 256) w[i] = src[i];
    __syncthreads();
    for (int k = t; k < 6400; k += 256) {
      int dhw = k >> 8, c = k & 255;
      BT[n * 6400 + k] = f2bf(w[c * 25 + dhw]);
    }
  } else {
    int idx = (bid - 4352) * 256 + t;
    int chunk = idx & 31;
    int pix = idx >> 5;
    int img = pix >= 1040;
    int p = pix - img * 1040;
    int h, w2;
    if (p < 528) {
      int rs = p / 132;
      h = (rs < 2) ? rs : rs + 128;
      w2 = p - rs * 132;
    } else {
      int q = p - 528;
      h = 2 + (q >> 2);
      int cs = q & 3;
      w2 = (cs < 2) ? cs : cs + 128;
    }
    us8 z = {0, 0, 0, 0, 0, 0, 0, 0};
    *(us8*)(Apad + (size_t)(img * 17424 + h * 132 + w2) * 256 + chunk * 8) = z;
  }
}

// --- shared K2 pieces -------------------------------------------------------
#define BAR() __builtin_amdgcn_s_barrier()
#define VMC(n) asm volatile("s_waitcnt vmcnt(" #n ")" ::: "memory")
#define SB0() __builtin_amdgcn_sched_barrier(0)
#define SP(n) __builtin_amdgcn_s_setprio(n)
#define MFMA_SET(AST, BST) do {                                                \
  _Pragma("unroll") for (int s_ = 0; s_ < 8; ++s_)                             \
  _Pragma("unroll") for (int j_ = 0; j_ < 4; ++j_)                             \
    acc[s_][j_] = __builtin_amdgcn_mfma_f32_16x16x32_bf16(                     \
        AST[s_], BST[j_], acc[s_][j_], 0, 0, 0); } while(0)
#define ADDR_SETUP(NBLK)                                                       \
  const int tid = threadIdx.x;                                                 \
  const int bid = blockIdx.x;                                                  \
  const int lid = (bid & 7) * (NBLK / 8) + (bid >> 3);                         \
  const int wid = tid >> 6;                                                    \
  const int l = tid & 63;                                                      \
  const int swz = (l & 3) ^ ((l >> 3) & 3);                                    \
  const int rl = l & 15, q = l >> 4;                                           \
  const int wm = wid >> 2, wn = wid & 3;                                       \
  const int areadbase = (wm * 128 + rl) * 32 + ((q ^ ((rl >> 1) & 3)) << 3);   \
  const int breadbase = (wn * 64 + rl) * 32 + ((q ^ ((rl >> 1) & 3)) << 3);
#define BASE_SETUP()                                                           \
  int abase0, abase1, bbase0, bbase1;                                          \
  {                                                                            \
    int ra = wid * 16 + (l >> 2);                                              \
    int m = m0 + ra;                                                           \
    int b = m >> 14, hw = m & 16383, h = hw >> 7, w = hw & 127;                \
    abase0 = ((b * 132 + h) * 132 + w) * 256 + swz * 8;                        \
    m = m0 + ra + 128;                                                         \
    b = m >> 14; hw = m & 16383; h = hw >> 7; w = hw & 127;                    \
    abase1 = ((b * 132 + h) * 132 + w) * 256 + swz * 8;                        \
    bbase0 = ra * 6400 + swz * 8;                                              \
    bbase1 = (ra + 128) * 6400 + swz * 8;                                      \
  }
#define EPILOGUE(PBUF)                                                         \
  _Pragma("unroll") for (int s = 0; s < 8; ++s)                                \
  _Pragma("unroll") for (int j = 0; j < 4; ++j) {                              \
    int col = wn * 64 + j * 16 + rl;                                           \
    int mrow = m0 + wm * 128 + s * 16 + (q << 2);                              \
    _Pragma("unroll") for (int e = 0; e < 4; ++e)                              \
      (PBUF)[(size_t)(mrow + e) * 256 + col] = f2bf(acc[s][j][e]);             \
  }

// --- K2a: split-K=2, 4-slot ring, VMC(4)/body (exact r8; fallback path) ----
#define STAGE4(slot, ku) do { int dhw_=(ku)>>3, dh_=dhw_/5, dw_=dhw_-dh_*5;    \
    int ao_=((dh_*132+dw_)<<8)+(((ku)&7)<<5);  int kp_=(ku)<<5;                \
    gld16(Aap+abase0+ao_, &As[slot][sA]);                                      \
    gld16(Aap+abase1+ao_, &As[slot][sA+4096]);                                 \
    gld16(BT+bbase0+kp_, &Bs[slot][sA]);                                       \
    gld16(BT+bbase1+kp_, &Bs[slot][sA+4096]); } while(0)
#define READ4(AST, BST, slot) do {                                             \
  _Pragma("unroll") for (int s_ = 0; s_ < 8; ++s_)                             \
    AST[s_] = *(const bf16x8*)(&As[slot][areadbase + s_*512]);                 \
  _Pragma("unroll") for (int j_ = 0; j_ < 4; ++j_)                             \
    BST[j_] = *(const bf16x8*)(&Bs[slot][breadbase + j_*512]); } while(0)

__global__ __launch_bounds__(512, 1) void caps_sk2(
    const unsigned short* __restrict__ Aap,
    const unsigned short* __restrict__ BT,
    unsigned short* __restrict__ Pp) {
  __shared__ __attribute__((aligned(16))) unsigned short As[4][8192];
  __shared__ __attribute__((aligned(16))) unsigned short Bs[4][8192];
  ADDR_SETUP(256)
  const int kid = lid & 1;
  const int m0 = (lid >> 1) << 8;
  const int t0 = kid * 100;
  BASE_SETUP()
  const int sA = wid * 512;

  f32x4 acc[8][4] = {};
  bf16x8 aR0[8], bR0[4], aR1[8], bR1[4];

  STAGE4(0, t0 + 0); STAGE4(1, t0 + 1); STAGE4(2, t0 + 2);
  VMC(4); BAR();
  READ4(aR0, bR0, 0);

  for (int it = 0; it < 48; ++it) {
    const int u = it * 2;
    READ4(aR1, bR1, (u + 1) & 3);
    STAGE4((u + 3) & 3, t0 + u + 3);
    SP(1); MFMA_SET(aR0, bR0); SP(0);
    VMC(4); SB0(); BAR();
    READ4(aR0, bR0, (u + 2) & 3);
    STAGE4((u + 4) & 3, t0 + u + 4);
    SP(1); MFMA_SET(aR1, bR1); SP(0);
    VMC(4); SB0(); BAR();
  }
  READ4(aR1, bR1, 1);
  STAGE4(3, t0 + 99);
  SP(1); MFMA_SET(aR0, bR0); SP(0);
  VMC(4); SB0(); BAR();
  READ4(aR0, bR0, 2);
  SP(1); MFMA_SET(aR1, bR1); SP(0);
  VMC(0); SB0(); BAR();
  READ4(aR1, bR1, 3);
  SP(1); MFMA_SET(aR0, bR0); SP(0);
  MFMA_SET(aR1, bR1);

  unsigned short* P = Pp + kid * 8388608;
  EPILOGUE(P)
}

// --- K2b: split-K=4, 2-slot ring, VMC(0)/body, 512 blocks = 2/CU ----------
// Sibling block's waves fill the VMC(0)/barrier bubbles (m97/m114 mechanism).
// Read-before-barrier / write-after-barrier = m201-verified idiom.
__global__ __launch_bounds__(512, 4) void caps_sk4(
    const unsigned short* __restrict__ Aap,
    const unsigned short* __restrict__ BT,
    unsigned short* __restrict__ Pp) {
  __shared__ __attribute__((aligned(16))) unsigned short As[2][8192];
  __shared__ __attribute__((aligned(16))) unsigned short Bs[2][8192];
  ADDR_SETUP(512)
  const int kid = lid & 3;
  const int m0 = (lid >> 2) << 8;
  const int t0 = kid * 50;             // 50 BK=32 units per quarter
  BASE_SETUP()
  const int sA = wid * 512;

  f32x4 acc[8][4] = {};
  bf16x8 aR0[8], bR0[4], aR1[8], bR1[4];

  // prologue: stage units 0,1; full drain; read unit 0; barrier
  STAGE4(0, t0 + 0); STAGE4(1, t0 + 1);
  VMC(0); BAR();
  READ4(aR0, bR0, 0);
  BAR();                               // protect slot0 from body-0 stage

  // bodies 0..47 (24 iters x 2); body b: read unit b+1, stage unit b+2
  for (int it = 0; it < 24; ++it) {
    const int u = it * 2;
    // body u (even): cur=set0; read slot (u+1)&1=1; stage slot u&1=0
    READ4(aR1, bR1, 1);
    STAGE4(0, t0 + u + 2);
    SP(1); MFMA_SET(aR0, bR0); SP(0);
    VMC(0); SB0(); BAR();
    // body u+1 (odd): cur=set1; read slot 0; stage slot 1
    READ4(aR0, bR0, 0);
    STAGE4(1, t0 + u + 3);
    SP(1); MFMA_SET(aR1, bR1); SP(0);
    VMC(0); SB0(); BAR();
  }
  // body 48: read unit 49 (slot 1, staged at body 47, drained); no stage
  READ4(aR1, bR1, 1);
  SP(1); MFMA_SET(aR0, bR0); SP(0);
  // body 49 (compiler inserts lgkm waits for aR1/bR1)
  MFMA_SET(aR1, bR1);

  unsigned short* P = Pp + kid * 8388608;
  EPILOGUE(P)
}

// --- K3: merge(NB partials) + squash + seg + recon, 2 threads/pixel --------
template <int NB>
__global__ __launch_bounds__(256) void tail_k(
    const unsigned short* __restrict__ Pp, const float* __restrict__ y,
    const float* __restrict__ bp, const float* __restrict__ cbp,
    const float* __restrict__ Ws, const float* __restrict__ bs,
    const float* __restrict__ cbs,
    const float* __restrict__ Wr1, const float* __restrict__ br1,
    const float* __restrict__ Wr2, const float* __restrict__ br2,
    const float* __restrict__ Wr3, const float* __restrict__ br3,
    float* __restrict__ out) {
  __shared__ float ccl[256];
  __shared__ float sbl[16];
  __shared__ float Wsl[128];
  __shared__ float W1l[1024];
  __shared__ float b1l[64];
  __shared__ float W2l[8192];
  __shared__ float b2l[128];
  __shared__ float W3l[128];

  const int tid = threadIdx.x;
  ccl[tid] = bp[tid] * (1.f / 32.f) + cbp[tid];
  if (tid < 16) sbl[tid] = 32.f * bs[tid] + cbs[tid];
  if (tid < 128) { Wsl[tid] = Ws[tid]; b2l[tid] = br2[tid]; W3l[tid] = Wr3[tid]; }
  if (tid < 64) b1l[tid] = br1[tid];
  for (int i = tid; i < 1024; i += 256) W1l[i] = Wr1[i];
  for (int i = tid; i < 8192; i += 256) W2l[i] = Wr2[i];
  __syncthreads();

  const int m = blockIdx.x * 128 + (tid >> 1);
  const int hf = tid & 1;

  const us8* pr[NB];
#pragma unroll
  for (int qb = 0; qb < NB; ++qb)
    pr[qb] = (const us8*)(Pp + (size_t)qb * 8388608 + (size_t)m * 256) + hf * 16;

  float P8[8] = {0.f, 0.f, 0.f, 0.f, 0.f, 0.f, 0.f, 0.f};
#pragma unroll 4
  for (int i = 0; i < 16; ++i) {
    const int ci = (hf * 16 + i) * 8;
    float v[8];
#pragma unroll
    for (int c = 0; c < 8; ++c) v[c] = 0.f;
#pragma unroll
    for (int qb = 0; qb < NB; ++qb) {
      us8 a = pr[qb][i];
#pragma unroll
      for (int c = 0; c < 8; ++c) v[c] += bf2f(a[c]);
    }
#pragma unroll
    for (int c = 0; c < 8; ++c) v[c] = v[c] * (1.f / 32.f) + ccl[ci + c];
    float sqa = v[0]*v[0] + v[1]*v[1] + v[2]*v[2] + v[3]*v[3];
    float sqb = v[4]*v[4] + v[5]*v[5] + v[6]*v[6] + v[7]*v[7];
    float sq = sqa + sqb;
    float scale = sq / ((1.f + sq) * sqrtf(sq + 1e-9f));
#pragma unroll
    for (int c = 0; c < 8; ++c) P8[c] += v[c] * scale;
  }
#pragma unroll
  for (int c = 0; c < 8; ++c) P8[c] += __shfl_xor(P8[c], 1);

  float pre[16];
  float sqx = 0.f, sqy = 0.f;
#pragma unroll
  for (int a = 0; a < 16; ++a) {
    float s0 = P8[0]*Wsl[a*8+0] + P8[1]*Wsl[a*8+1] + P8[2]*Wsl[a*8+2] + P8[3]*Wsl[a*8+3];
    float s1 = P8[4]*Wsl[a*8+4] + P8[5]*Wsl[a*8+5] + P8[6]*Wsl[a*8+6] + P8[7]*Wsl[a*8+7];
    float s = sbl[a] + s0 + s1;
    pre[a] = s;
    if (a & 1) sqy += s * s; else sqx += s * s;
  }
  float sq2 = sqx + sqy;
  float sc2 = sq2 / ((1.f + sq2) * sqrtf(sq2 + 1e-9f));
  if (hf == 0) out[m] = sqrtf(sq2 * sc2 * sc2 + 1e-9f);

  const float f = sc2 * y[m];
  float r1o[32];
#pragma unroll
  for (int jj = 0; jj < 32; ++jj) {
    const float* wr = W1l + (hf * 32 + jj) * 16;
    float s0 = 0.f, s1 = 0.f;
#pragma unroll
    for (int a = 0; a < 8; ++a) { s0 += pre[a] * f * wr[a]; s1 += pre[a+8] * f * wr[a+8]; }
    r1o[jj] = fmaxf(b1l[hf * 32 + jj] + s0 + s1, 0.f);
  }
  float lo[32], hi[32];
#pragma unroll
  for (int jj = 0; jj < 32; ++jj) {
    float tmp = __shfl_xor(r1o[jj], 1);
    lo[jj] = hf ? tmp : r1o[jj];
    hi[jj] = hf ? r1o[jj] : tmp;
  }
  float a0 = 0.f, a1 = 0.f, a2 = 0.f, a3 = 0.f;
#pragma unroll 4
  for (int kk = 0; kk < 64; ++kk) {
    const int k = hf * 64 + kk;
    const float* w = W2l + k * 64;
    float s0 = 0.f, s1 = 0.f, s2 = 0.f, s3 = 0.f;
#pragma unroll
    for (int j = 0; j < 8; ++j) {
      s0 += lo[j] * w[j];           s1 += lo[j + 8] * w[j + 8];
      s2 += lo[j + 16] * w[j + 16]; s3 += lo[j + 24] * w[j + 24];
    }
#pragma unroll
    for (int j = 0; j < 8; ++j) {
      s0 += hi[j] * w[32 + j];      s1 += hi[j + 8] * w[40 + j];
      s2 += hi[j + 16] * w[48 + j]; s3 += hi[j + 24] * w[56 + j];
    }
    float s = b2l[k] + (s0 + s1) + (s2 + s3);
    float t = fmaxf(s, 0.f) * W3l[k];
    switch (kk & 3) { case 0: a0 += t; break; case 1: a1 += t; break;
                      case 2: a2 += t; break; default: a3 += t; }
  }
  float own = (a0 + a1) + (a2 + a3);
  float acc2 = br3[0] + own + __shfl_xor(own, 1);
  if (hf == 0) out[32768 + m] = 1.f / (1.f + expf(-acc2));
}

// ---------------------------------------------------------------------------
extern "C" void kernel_launch(void* const* d_in, const int* in_sizes, int n_in,
                              void* d_out, int out_size, void* d_ws, size_t ws_size,
                              hipStream_t stream) {
  const float* x   = (const float*)d_in[0];
  const float* y   = (const float*)d_in[1];
  const float* W1  = (const float*)d_in[2];
  const float* b1  = (const float*)d_in[3];
  const float* Wp  = (const float*)d_in[4];
  const float* bp  = (const float*)d_in[5];
  const float* cbp = (const float*)d_in[6];
  const float* Ws  = (const float*)d_in[7];
  const float* bs  = (const float*)d_in[8];
  const float* cbs = (const float*)d_in[9];
  const float* Wr1 = (const float*)d_in[10];
  const float* br1 = (const float*)d_in[11];
  const float* Wr2 = (const float*)d_in[12];
  const float* br2 = (const float*)d_in[13];
  const float* Wr3 = (const float*)d_in[14];
  const float* br3 = (const float*)d_in[15];
  float* out = (float*)d_out;

  char* ws = (char*)d_ws;
  unsigned short* Apad = (unsigned short*)ws;
  unsigned short* BT   = (unsigned short*)(ws + BT_OFF);
  unsigned short* Pp   = (unsigned short*)(ws + PP_OFF);

  hipLaunchKernelGGL(pre_k, dim3(4612), dim3(256), 0, stream, x, W1, b1, Wp, BT, Apad);
  if (ws_size >= SK4_BYTES) {
    hipLaunchKernelGGL(caps_sk4, dim3(512), dim3(512), 0, stream, Apad, BT, Pp);
    hipLaunchKernelGGL(tail_k<4>, dim3(256), dim3(256), 0, stream,
                       Pp, y, bp, cbp, Ws, bs, cbs, Wr1, br1, Wr2, br2, Wr3, br3, out);
  } else {
    hipLaunchKernelGGL(caps_sk2, dim3(256), dim3(512), 0, stream, Apad, BT, Pp);
    hipLaunchKernelGGL(tail_k<2>, dim3(256), dim3(256), 0, stream,
                       Pp, y, bp, cbp, Ws, bs, cbs, Wr1, br1, Wr2, br2, Wr3, br3, out);
  }
}

// Round 11
// 144.492 us; speedup vs baseline: 12.4936x; 12.4936x over previous
//
#include <hip/hip_runtime.h>
#include <hip/hip_bf16.h>

typedef __attribute__((ext_vector_type(8))) unsigned short us8;
typedef __attribute__((ext_vector_type(8))) __bf16 bf16x8;
typedef __attribute__((ext_vector_type(4))) float f32x4;

__device__ __forceinline__ unsigned short f2bf(float f) {
  unsigned int u = __float_as_uint(f);
  u += 0x7FFFu + ((u >> 16) & 1u);   // round-to-nearest-even
  return (unsigned short)(u >> 16);
}
__device__ __forceinline__ float bf2f(unsigned short u) {
  return __uint_as_float(((unsigned int)u) << 16);
}

// direct global->LDS DMA, 16B per lane (dest = wave-uniform base + lane*16)
__device__ __forceinline__ void gld16(const unsigned short* g, unsigned short* l) {
  __builtin_amdgcn_global_load_lds(reinterpret_cast<const unsigned int*>(g),
                                   reinterpret_cast<unsigned int*>(l), 16, 0, 0);
}

// ---------------------------------------------------------------------------
// ws layout (bytes)
//   Apad : [2][132][132][256] bf16 = 17,842,176
//   BT   : [256][6400] bf16 (k=(dh*5+dw)*256+c)
//   Pp   : 2 x [32768][256] bf16 partials = 33,554,432
// total = 54,673,408
// ---------------------------------------------------------------------------
#define BT_OFF     17842176
#define PP_OFF     21118976

// --- K1: fused conv1 (blocks 0..4095) + weight prep (4096..4351) +
//         halo zero (4352..4611) --------------------------------------------
__global__ __launch_bounds__(256) void pre_k(const float* __restrict__ x,
                                             const float* __restrict__ W1,
                                             const float* __restrict__ b1,
                                             const float* __restrict__ Wp,
                                             unsigned short* __restrict__ BT,
                                             unsigned short* __restrict__ Apad) {
  __shared__ float w[6400];
  const int bid = blockIdx.x, t = threadIdx.x;
  if (bid < 4096) {
    int pxt = bid >> 3;
    int cq  = bid & 7;
    int px  = (pxt << 6) + (t & 63);
    int cg  = __builtin_amdgcn_readfirstlane(t >> 6);
    int co0 = (cq << 5) + (cg << 3);
    int b = px >> 14, hw = px & 16383;
    int h = hw >> 7, wcol = hw & 127;

    float patch[25];
#pragma unroll
    for (int dh = 0; dh < 5; ++dh)
#pragma unroll
      for (int dw = 0; dw < 5; ++dw) {
        int hh = h + dh - 2, ww = wcol + dw - 2;
        bool ok = (hh >= 0) & (hh < 128) & (ww >= 0) & (ww < 128);
        patch[dh * 5 + dw] = ok ? x[(b << 14) + hh * 128 + ww] : 0.f;
      }
    us8 o;
#pragma unroll
    for (int c = 0; c < 8; ++c) {
      float acc = b1[co0 + c];
#pragma unroll
      for (int i = 0; i < 25; ++i) acc += patch[i] * W1[(co0 + c) * 25 + i];
      o[c] = f2bf(fmaxf(acc, 0.f));
    }
    *(us8*)(Apad + (size_t)((b * 132 + h + 2) * 132 + (wcol + 2)) * 256 + co0) = o;
  } else if (bid < 4352) {
    const int n = bid - 4096;
    const float* src = Wp + n * 6400;
    for (int i = t; i < 6400; i += 256) w[i] = src[i];
    __syncthreads();
    for (int k = t; k < 6400; k += 256) {
      int dhw = k >> 8, c = k & 255;
      BT[n * 6400 + k] = f2bf(w[c * 25 + dhw]);
    }
  } else {
    int idx = (bid - 4352) * 256 + t;
    int chunk = idx & 31;
    int pix = idx >> 5;
    int img = pix >= 1040;
    int p = pix - img * 1040;
    int h, w2;
    if (p < 528) {
      int rs = p / 132;
      h = (rs < 2) ? rs : rs + 128;
      w2 = p - rs * 132;
    } else {
      int q = p - 528;
      h = 2 + (q >> 2);
      int cs = q & 3;
      w2 = (cs < 2) ? cs : cs + 128;
    }
    us8 z = {0, 0, 0, 0, 0, 0, 0, 0};
    *(us8*)(Apad + (size_t)(img * 17424 + h * 132 + w2) * 256 + chunk * 8) = z;
  }
}

// --- K2: implicit-GEMM conv (EXACT r8 config: 96.8us, MfmaUtil 47, 0 confl) -
// 256x256 tile, 8 waves, split-K=2, 4-slot BK=32 ring (A+B in LDS, 128 KB),
// reg-double-buffered frags, ONE barrier + ONE counted VMC(4) per k-unit.
#define STAGE(slot, ku) do { int dhw_=(ku)>>3, dh_=dhw_/5, dw_=dhw_-dh_*5;     \
    int ao_=((dh_*132+dw_)<<8)+(((ku)&7)<<5);                                  \
    int kp_=(ku)<<5;                                                           \
    gld16(Aap+abase0+ao_, &As[slot][sA]);                                      \
    gld16(Aap+abase1+ao_, &As[slot][sA+4096]);                                 \
    gld16(BT+bbase0+kp_, &Bs[slot][sA]);                                       \
    gld16(BT+bbase1+kp_, &Bs[slot][sA+4096]); } while(0)
#define READ_SET(AST, BST, slot) do {                                          \
  _Pragma("unroll") for (int s_ = 0; s_ < 8; ++s_)                             \
    AST[s_] = *(const bf16x8*)(&As[slot][areadbase + s_*512]);                 \
  _Pragma("unroll") for (int j_ = 0; j_ < 4; ++j_)                             \
    BST[j_] = *(const bf16x8*)(&Bs[slot][breadbase + j_*512]); } while(0)
#define MFMA_SET(AST, BST) do {                                                \
  _Pragma("unroll") for (int s_ = 0; s_ < 8; ++s_)                             \
  _Pragma("unroll") for (int j_ = 0; j_ < 4; ++j_)                             \
    acc[s_][j_] = __builtin_amdgcn_mfma_f32_16x16x32_bf16(                     \
        AST[s_], BST[j_], acc[s_][j_], 0, 0, 0); } while(0)
#define BAR() __builtin_amdgcn_s_barrier()
#define VMC(n) asm volatile("s_waitcnt vmcnt(" #n ")" ::: "memory")
#define SB0() __builtin_amdgcn_sched_barrier(0)
#define SP(n) __builtin_amdgcn_s_setprio(n)

__global__ __launch_bounds__(512, 1) void caps_conv2(
    const unsigned short* __restrict__ Aap,  // Apad NHWC bf16
    const unsigned short* __restrict__ BT,   // [256][6400] bf16
    unsigned short* __restrict__ Pp)         // 2 x [32768][256] bf16 partials
{
  __shared__ __attribute__((aligned(16))) unsigned short As[4][8192];
  __shared__ __attribute__((aligned(16))) unsigned short Bs[4][8192];

  const int tid = threadIdx.x;
  const int bid = blockIdx.x;          // 256 blocks
  const int lid = (bid & 7) * 32 + (bid >> 3);   // bijective XCD-chunked swizzle
  const int kid = lid & 1;
  const int m0 = (lid >> 1) << 8;
  const int t0 = kid * 100;            // 100 k-units of 32 per split-K half
  const int wid = tid >> 6;
  const int l = tid & 63;

  const int swz = (l & 3) ^ ((l >> 3) & 3);   // matches read part q^((row>>1)&3)
  int abase0, abase1, bbase0, bbase1;
  {
    int ra = wid * 16 + (l >> 2);               // 0..127
    int m = m0 + ra;
    int b = m >> 14, hw = m & 16383, h = hw >> 7, w = hw & 127;
    abase0 = ((b * 132 + h) * 132 + w) * 256 + swz * 8;
    m = m0 + ra + 128;
    b = m >> 14; hw = m & 16383; h = hw >> 7; w = hw & 127;
    abase1 = ((b * 132 + h) * 132 + w) * 256 + swz * 8;
    bbase0 = ra * 6400 + swz * 8;
    bbase1 = (ra + 128) * 6400 + swz * 8;
  }
  const int sA = wid * 512;            // LDS stage base (ushorts)

  const int rl = l & 15, q = l >> 4;
  const int wm = wid >> 2, wn = wid & 3;       // 2x4 wave grid, tile 128x64
  const int areadbase = (wm * 128 + rl) * 32 + ((q ^ ((rl >> 1) & 3)) << 3);
  const int breadbase = (wn * 64 + rl) * 32 + ((q ^ ((rl >> 1) & 3)) << 3);

  f32x4 acc[8][4] = {};
  bf16x8 aR0[8], bR0[4], aR1[8], bR1[4];

  STAGE(0, t0 + 0); STAGE(1, t0 + 1); STAGE(2, t0 + 2);
  VMC(4); BAR();
  READ_SET(aR0, bR0, 0);

  for (int it = 0; it < 48; ++it) {
    const int u = it * 2;
    READ_SET(aR1, bR1, (u + 1) & 3);
    STAGE((u + 3) & 3, t0 + u + 3);
    SP(1); MFMA_SET(aR0, bR0); SP(0);
    VMC(4); SB0(); BAR();
    READ_SET(aR0, bR0, (u + 2) & 3);
    STAGE((u + 4) & 3, t0 + u + 4);
    SP(1); MFMA_SET(aR1, bR1); SP(0);
    VMC(4); SB0(); BAR();
  }
  READ_SET(aR1, bR1, 1);
  STAGE(3, t0 + 99);
  SP(1); MFMA_SET(aR0, bR0); SP(0);
  VMC(4); SB0(); BAR();
  READ_SET(aR0, bR0, 2);
  SP(1); MFMA_SET(aR1, bR1); SP(0);
  VMC(0); SB0(); BAR();
  READ_SET(aR1, bR1, 3);
  SP(1); MFMA_SET(aR0, bR0); SP(0);
  MFMA_SET(aR1, bR1);

  unsigned short* P = Pp + kid * 8388608;
#pragma unroll
  for (int s = 0; s < 8; ++s) {
#pragma unroll
    for (int j = 0; j < 4; ++j) {
      int col = wn * 64 + j * 16 + rl;
      int mrow = m0 + wm * 128 + s * 16 + (q << 2);
#pragma unroll
      for (int e = 0; e < 4; ++e)
        P[(size_t)(mrow + e) * 256 + col] = f2bf(acc[s][j][e]);
    }
  }
}

// --- K3: tail, scalarized weights -------------------------------------------
// 512 blocks x 128 threads. lane = pixel (64/block), 2 waves split the
// {capsule-merge, r1-j, recon-k} ranges. ALL weight/bias indices are
// wave-uniform (loop counters + readfirstlane'd wave id) -> compiler emits
// s_load + v_fmac(s,v): weight traffic goes to the scalar cache, NOT LDS
// (removes the 1 GB/dispatch LDS-read floor of the old per-thread W2 walk).
__global__ __launch_bounds__(128) void tail_k4(
    const unsigned short* __restrict__ Pp, const float* __restrict__ y,
    const float* __restrict__ bp, const float* __restrict__ cbp,
    const float* __restrict__ Ws, const float* __restrict__ bs,
    const float* __restrict__ cbs,
    const float* __restrict__ Wr1, const float* __restrict__ br1,
    const float* __restrict__ Wr2, const float* __restrict__ br2,
    const float* __restrict__ Wr3, const float* __restrict__ br3,
    float* __restrict__ out) {
  __shared__ float pp[2][64][8];     // per-wave merge partials
  __shared__ float r1l[64][65];      // r1 exchange (+1 pad: conflict-free)
  __shared__ float snk[2][64];       // recon partial sums

  const int tid = threadIdx.x;
  const int w = __builtin_amdgcn_readfirstlane(tid >> 6);  // wave id 0/1 (SGPR)
  const int l = tid & 63;                                   // lane = local pixel
  const int m = blockIdx.x * 64 + l;

  // --- phase 1: merge+squash capsules [w*16, w*16+16) ---
  const us8* pr0 = (const us8*)(Pp + (size_t)m * 256) + w * 16;
  const us8* pr1 = (const us8*)(Pp + 8388608 + (size_t)m * 256) + w * 16;
  float P8[8] = {0.f, 0.f, 0.f, 0.f, 0.f, 0.f, 0.f, 0.f};
#pragma unroll 4
  for (int i = 0; i < 16; ++i) {
    const int ci = (w * 16 + i) * 8;          // uniform -> bp/cbp scalarize
    us8 a = pr0[i], b = pr1[i];
    float v[8];
#pragma unroll
    for (int c = 0; c < 8; ++c)
      v[c] = (bf2f(a[c]) + bf2f(b[c])) * (1.f / 32.f)
           + (bp[ci + c] * (1.f / 32.f) + cbp[ci + c]);
    float sqa = v[0]*v[0] + v[1]*v[1] + v[2]*v[2] + v[3]*v[3];
    float sqb = v[4]*v[4] + v[5]*v[5] + v[6]*v[6] + v[7]*v[7];
    float sq = sqa + sqb;
    float scale = sq / ((1.f + sq) * sqrtf(sq + 1e-9f));
#pragma unroll
    for (int c = 0; c < 8; ++c) P8[c] += v[c] * scale;
  }
#pragma unroll
  for (int c = 0; c < 8; ++c) pp[w][l][c] = P8[c];
  __syncthreads();
#pragma unroll
  for (int c = 0; c < 8; ++c) P8[c] = pp[0][l][c] + pp[1][l][c];

  // --- phase 2: seg preact + squash + length (both waves; uniform Ws/bs) ---
  float pre[16];
  float sqx = 0.f, sqy = 0.f;
#pragma unroll
  for (int a = 0; a < 16; ++a) {
    float s0 = P8[0]*Ws[a*8+0] + P8[1]*Ws[a*8+1] + P8[2]*Ws[a*8+2] + P8[3]*Ws[a*8+3];
    float s1 = P8[4]*Ws[a*8+4] + P8[5]*Ws[a*8+5] + P8[6]*Ws[a*8+6] + P8[7]*Ws[a*8+7];
    float s = (32.f * bs[a] + cbs[a]) + s0 + s1;
    pre[a] = s;
    if (a & 1) sqy += s * s; else sqx += s * s;
  }
  float sq2 = sqx + sqy;
  float sc2 = sq2 / ((1.f + sq2) * sqrtf(sq2 + 1e-9f));
  if (w == 0) out[m] = sqrtf(sq2 * sc2 * sc2 + 1e-9f);

  const float f = sc2 * y[m];
  float pf[16];
#pragma unroll
  for (int a = 0; a < 16; ++a) pf[a] = pre[a] * f;

  // --- phase 3: r1 half j = w*32 + jj (uniform Wr1/br1) ---
#pragma unroll
  for (int jj = 0; jj < 32; ++jj) {
    const int j = w * 32 + jj;                // uniform
    float s0 = 0.f, s1 = 0.f;
#pragma unroll
    for (int a = 0; a < 8; ++a) {
      s0 += pf[a] * Wr1[j * 16 + a];
      s1 += pf[a + 8] * Wr1[j * 16 + a + 8];
    }
    r1l[l][j] = fmaxf(br1[j] + s0 + s1, 0.f);
  }
  __syncthreads();
  float r1f[64];
#pragma unroll
  for (int j = 0; j < 64; ++j) r1f[j] = r1l[l][j];

  // --- phase 4: recon half k = w*64 + kk (uniform Wr2/br2/Wr3) ---
  float a0 = 0.f, a1 = 0.f, a2 = 0.f, a3 = 0.f;
#pragma unroll 4
  for (int kk = 0; kk < 64; ++kk) {
    const int k = w * 64 + kk;                // uniform
    const float* wr = Wr2 + k * 64;
    float s0 = 0.f, s1 = 0.f, s2 = 0.f, s3 = 0.f;
#pragma unroll
    for (int j = 0; j < 16; ++j) {
      s0 += r1f[j] * wr[j];           s1 += r1f[j + 16] * wr[j + 16];
      s2 += r1f[j + 32] * wr[j + 32]; s3 += r1f[j + 48] * wr[j + 48];
    }
    float s = br2[k] + (s0 + s1) + (s2 + s3);
    float t = fmaxf(s, 0.f) * Wr3[k];
    switch (kk & 3) { case 0: a0 += t; break; case 1: a1 += t; break;
                      case 2: a2 += t; break; default: a3 += t; }
  }
  float own = (a0 + a1) + (a2 + a3);
  snk[w][l] = own;
  __syncthreads();
  if (w == 0) {
    float acc2 = br3[0] + own + snk[1][l];
    out[32768 + m] = 1.f / (1.f + expf(-acc2));
  }
}

// ---------------------------------------------------------------------------
extern "C" void kernel_launch(void* const* d_in, const int* in_sizes, int n_in,
                              void* d_out, int out_size, void* d_ws, size_t ws_size,
                              hipStream_t stream) {
  const float* x   = (const float*)d_in[0];
  const float* y   = (const float*)d_in[1];
  const float* W1  = (const float*)d_in[2];
  const float* b1  = (const float*)d_in[3];
  const float* Wp  = (const float*)d_in[4];
  const float* bp  = (const float*)d_in[5];
  const float* cbp = (const float*)d_in[6];
  const float* Ws  = (const float*)d_in[7];
  const float* bs  = (const float*)d_in[8];
  const float* cbs = (const float*)d_in[9];
  const float* Wr1 = (const float*)d_in[10];
  const float* br1 = (const float*)d_in[11];
  const float* Wr2 = (const float*)d_in[12];
  const float* br2 = (const float*)d_in[13];
  const float* Wr3 = (const float*)d_in[14];
  const float* br3 = (const float*)d_in[15];
  float* out = (float*)d_out;

  char* ws = (char*)d_ws;
  unsigned short* Apad = (unsigned short*)ws;
  unsigned short* BT   = (unsigned short*)(ws + BT_OFF);
  unsigned short* Pp   = (unsigned short*)(ws + PP_OFF);

  hipLaunchKernelGGL(pre_k, dim3(4612), dim3(256), 0, stream, x, W1, b1, Wp, BT, Apad);
  hipLaunchKernelGGL(caps_conv2, dim3(256), dim3(512), 0, stream, Apad, BT, Pp);
  hipLaunchKernelGGL(tail_k4, dim3(512), dim3(128), 0, stream,
                     Pp, y, bp, cbp, Ws, bs, cbs, Wr1, br1, Wr2, br2, Wr3, br3, out);
}